// Round 2
// baseline (96.832 us; speedup 1.0000x reference)
//
#include <hip/hip_runtime.h>

#define CIN  32
#define OCH  64
#define HH   56
#define WW   56
#define BB   4
#define OT   4                  // output channels per block
#define IMG  (HH * WW)          // 3136
#define NW   18432              // 64*32*3*3
#define PH   58
#define PW   58
#define PIMG (PH * PW)          // 3364 padded image
#define NPAD (BB * CIN * PIMG)  // 430592 padded elements
#define PADBLKS (NPAD / 256)    // 1682 (exact)
#define XOFF 64                 // padded x starts at ws + 64 floats (256B aligned)

typedef float vf2 __attribute__((ext_vector_type(2)));  // -> v_pk_add_f32

// One dispatch does BOTH jobs:
//   blocks 0..1681 : write zero-padded (B,C,58,58) copy of x into ws+XOFF
//   block  1682    : |w| mean -> ws[0]  (single block, plain store, no atomic)
__global__ __launch_bounds__(256) void prep(const float* __restrict__ x,
                                            const float* __restrict__ w,
                                            float* __restrict__ ws) {
    if (blockIdx.x == PADBLKS) {
        float s = 0.f;
        const float4* w4 = reinterpret_cast<const float4*>(w);
        #pragma unroll
        for (int k = 0; k < 18; ++k) {
            float4 v = w4[k * 256 + threadIdx.x];
            s += fabsf(v.x) + fabsf(v.y) + fabsf(v.z) + fabsf(v.w);
        }
        #pragma unroll
        for (int off = 32; off; off >>= 1) s += __shfl_down(s, off);
        __shared__ float sm[4];
        if ((threadIdx.x & 63) == 0) sm[threadIdx.x >> 6] = s;
        __syncthreads();
        if (threadIdx.x == 0)
            ws[0] = (sm[0] + sm[1] + sm[2] + sm[3]) * (1.0f / (float)NW);
        return;
    }
    int idx = blockIdx.x * 256 + threadIdx.x;          // 0..NPAD-1
    int bc  = idx / PIMG;
    int r   = idx - bc * PIMG;
    int ph  = r / PW;
    int pw  = r - ph * PW;
    int hh  = ph - 1, wc = pw - 1;
    float v = 0.f;
    if ((unsigned)hh < (unsigned)HH && (unsigned)wc < (unsigned)WW)
        v = x[bc * IMG + hh * WW + wc];                // coalesced within rows
    ws[XOFF + idx] = v;
}

// block = 128 threads = 2 waves over the SAME 64 pixels; wave wv handles
// channels [wv*16, wv*16+16). Doubles resident waves (12 -> 24 per CU) with
// no extra x-load or min/add work; one LDS exchange combines the halves.
// Channel pairs pack the tap adds as v_pk_add_f32 with no scalar remainder.
__global__ __launch_bounds__(128) void minconv_kernel(const float* __restrict__ ws,
                                                      const float* __restrict__ wts,
                                                      float* __restrict__ out) {
    const float* xp = ws + XOFF;
    const int lane = threadIdx.x & 63;
    const int wv   = threadIdx.x >> 6;                 // 0/1: channel half
    const int hw = blockIdx.x * 64 + lane;             // 0..3135 exact
    const int o0 = blockIdx.y * OT;
    const int b  = blockIdx.z;
    const int h  = hw / WW;
    const int w  = hw - h * WW;

    const float mu = ws[0];                            // uniform s_load, issued early

    // lane base for this (b, c-half, pixel); taps at +kh*PW+kw, channel B at +PIMG
    const float* xq = xp + (size_t)b * (CIN * PIMG) + (wv * 16) * PIMG + h * PW + w;
    const float* wb = wts + o0 * (CIN * 9) + (wv * 16) * 9;   // wave-uniform -> s_load

    vf2 acc[OT];
    #pragma unroll
    for (int oo = 0; oo < OT; ++oo) acc[oo] = (vf2)(0.f);

    #pragma unroll
    for (int cp = 0; cp < 8; ++cp) {                   // 8 channel-pairs per wave
        const float* xA = xq + cp * 2 * PIMG;          // channel 2cp   (imm offsets fit)
        const float* xB = xA + PIMG;                   // channel 2cp+1
        float xa[9], xc[9];
        #pragma unroll
        for (int kh = 0; kh < 3; ++kh)
            #pragma unroll
            for (int kw = 0; kw < 3; ++kw) {
                xa[kh * 3 + kw] = xA[kh * PW + kw];
                xc[kh * 3 + kw] = xB[kh * PW + kw];
            }
        #pragma unroll
        for (int oo = 0; oo < OT; ++oo) {
            const float* wpA = wb + oo * (CIN * 9) + cp * 18;  // uniform -> s_load
            const float* wpB = wpA + 9;
            #pragma unroll
            for (int t = 0; t < 9; ++t) {
                vf2 m;
                m.x = fminf(xa[t], wpA[t]);
                m.y = fminf(xc[t], wpB[t]);
                acc[oo] += m;                          // v_pk_add_f32
            }
        }
    }

    // symmetric cross-wave combine: wave0 keeps oo 0,1; wave1 keeps oo 2,3
    __shared__ vf2 red[2][2][64];                      // [src_wave][j][lane], 2 KiB
    #pragma unroll
    for (int j = 0; j < 2; ++j)
        red[wv][j][lane] = acc[(wv ? 0 : 2) + j];      // give away the other pair
    __syncthreads();

    float* ob = out + ((size_t)b * OCH + o0) * IMG + hw;
    #pragma unroll
    for (int j = 0; j < 2; ++j) {
        int oo = wv * 2 + j;                           // pair this wave owns
        vf2 s = acc[oo] + red[1 - wv][j][lane];
        ob[oo * IMG] = mu * (s.x + s.y);
    }
}

extern "C" void kernel_launch(void* const* d_in, const int* in_sizes, int n_in,
                              void* d_out, int out_size, void* d_ws, size_t ws_size,
                              hipStream_t stream) {
    const float* x   = (const float*)d_in[0];   // 4*32*56*56
    const float* w   = (const float*)d_in[1];   // 64*32*3*3
    float*       out = (float*)d_out;           // 4*64*56*56
    float*       ws  = (float*)d_ws;

    prep<<<PADBLKS + 1, 256, 0, stream>>>(x, w, ws);
    dim3 grid(IMG / 64, OCH / OT, BB);          // 49 x 16 x 4 = 3136 blocks
    minconv_kernel<<<grid, 128, 0, stream>>>(ws, w, out);
}

// Round 3
// 95.941 us; speedup vs baseline: 1.0093x; 1.0093x over previous
//
#include <hip/hip_runtime.h>

#define CIN  32
#define OCH  64
#define HH   56
#define WW   56
#define BB   4
#define OT   4                  // output channels per block
#define IMG  (HH * WW)          // 3136
#define NW   18432              // 64*32*3*3
#define PH   58
#define PW   58
#define PIMG (PH * PW)          // 3364 padded image
#define NPAD (BB * CIN * PIMG)  // 430592 padded elements
#define PADBLKS (NPAD / 256)    // 1682 (exact)
#define XOFF 64                 // padded x starts at ws + 64 floats (256B aligned)

typedef float vf2 __attribute__((ext_vector_type(2)));  // -> v_pk_add_f32

// One dispatch does BOTH jobs:
//   blocks 0..1681 : write zero-padded (B,C,58,58) copy of x into ws+XOFF
//   block  1682    : |w| mean -> ws[0]  (single block, plain store, no atomic)
__global__ __launch_bounds__(256) void prep(const float* __restrict__ x,
                                            const float* __restrict__ w,
                                            float* __restrict__ ws) {
    if (blockIdx.x == PADBLKS) {
        float s = 0.f;
        const float4* w4 = reinterpret_cast<const float4*>(w);
        #pragma unroll
        for (int k = 0; k < 18; ++k) {
            float4 v = w4[k * 256 + threadIdx.x];
            s += fabsf(v.x) + fabsf(v.y) + fabsf(v.z) + fabsf(v.w);
        }
        #pragma unroll
        for (int off = 32; off; off >>= 1) s += __shfl_down(s, off);
        __shared__ float sm[4];
        if ((threadIdx.x & 63) == 0) sm[threadIdx.x >> 6] = s;
        __syncthreads();
        if (threadIdx.x == 0)
            ws[0] = (sm[0] + sm[1] + sm[2] + sm[3]) * (1.0f / (float)NW);
        return;
    }
    int idx = blockIdx.x * 256 + threadIdx.x;          // 0..NPAD-1
    int bc  = idx / PIMG;
    int r   = idx - bc * PIMG;
    int ph  = r / PW;
    int pw  = r - ph * PW;
    int hh  = ph - 1, wc = pw - 1;
    float v = 0.f;
    if ((unsigned)hh < (unsigned)HH && (unsigned)wc < (unsigned)WW)
        v = x[bc * IMG + hh * WW + wc];                // coalesced within rows
    ws[XOFF + idx] = v;
}

// block = 128 threads = 2 waves over the SAME 64 pixels; wave wv handles
// channels [wv*16, wv*16+16). 2x resident waves vs R1 with no extra x/w work.
// CRITICAL: every acc[] index is a compile-time literal (runtime-indexed
// ext_vector arrays demote to scratch -- that was R2's 6x regression).
__global__ __launch_bounds__(128) void minconv_kernel(const float* __restrict__ ws,
                                                      const float* __restrict__ wts,
                                                      float* __restrict__ out) {
    const float* xp = ws + XOFF;
    const int lane = threadIdx.x & 63;
    const int wv   = threadIdx.x >> 6;                 // 0/1: channel half
    const int hw = blockIdx.x * 64 + lane;             // 0..3135 exact
    const int o0 = blockIdx.y * OT;
    const int b  = blockIdx.z;
    const int h  = hw / WW;
    const int w  = hw - h * WW;

    const float mu = ws[0];                            // uniform s_load, issued early

    // lane base for this (b, c-half, pixel); taps at +kh*PW+kw, channel B at +PIMG
    const float* xq = xp + (size_t)b * (CIN * PIMG) + (wv * 16) * PIMG + h * PW + w;
    const float* wb = wts + o0 * (CIN * 9) + (wv * 16) * 9;   // wave-uniform -> s_load

    vf2 acc0 = (vf2)(0.f), acc1 = (vf2)(0.f);
    vf2 acc2 = (vf2)(0.f), acc3 = (vf2)(0.f);

    #pragma unroll
    for (int cp = 0; cp < 8; ++cp) {                   // 8 channel-pairs per wave
        const float* xA = xq + cp * 2 * PIMG;          // channel 2cp
        const float* xB = xA + PIMG;                   // channel 2cp+1
        float xa[9], xc[9];
        #pragma unroll
        for (int kh = 0; kh < 3; ++kh)
            #pragma unroll
            for (int kw = 0; kw < 3; ++kw) {
                xa[kh * 3 + kw] = xA[kh * PW + kw];
                xc[kh * 3 + kw] = xB[kh * PW + kw];
            }
        #pragma unroll
        for (int oo = 0; oo < OT; ++oo) {
            const float* wpA = wb + oo * (CIN * 9) + cp * 18;  // uniform -> s_load
            const float* wpB = wpA + 9;
            vf2 a = (vf2)(0.f);
            #pragma unroll
            for (int t = 0; t < 9; ++t) {
                vf2 m;
                m.x = fminf(xa[t], wpA[t]);
                m.y = fminf(xc[t], wpB[t]);
                a += m;                                // v_pk_add_f32
            }
            // literal-indexed accumulate (oo is a compile-time unroll constant,
            // but guard with switch so no runtime-indexed array ever exists)
            switch (oo) {
                case 0: acc0 += a; break;
                case 1: acc1 += a; break;
                case 2: acc2 += a; break;
                case 3: acc3 += a; break;
            }
        }
    }

    // cross-wave combine: wave0 keeps oo 0,1; wave1 keeps oo 2,3.
    // Wave-uniform branch, literal acc indices everywhere.
    __shared__ vf2 red[2][2][64];                      // [src_wave][j][lane], 2 KiB
    if (wv == 0) {
        red[0][0][lane] = acc2;
        red[0][1][lane] = acc3;
    } else {
        red[1][0][lane] = acc0;
        red[1][1][lane] = acc1;
    }
    __syncthreads();

    float* ob = out + ((size_t)b * OCH + o0) * IMG + hw;
    if (wv == 0) {
        vf2 s0 = acc0 + red[1][0][lane];
        vf2 s1 = acc1 + red[1][1][lane];
        ob[0]       = mu * (s0.x + s0.y);
        ob[IMG]     = mu * (s1.x + s1.y);
    } else {
        vf2 s0 = acc2 + red[0][0][lane];
        vf2 s1 = acc3 + red[0][1][lane];
        ob[2 * IMG] = mu * (s0.x + s0.y);
        ob[3 * IMG] = mu * (s1.x + s1.y);
    }
}

extern "C" void kernel_launch(void* const* d_in, const int* in_sizes, int n_in,
                              void* d_out, int out_size, void* d_ws, size_t ws_size,
                              hipStream_t stream) {
    const float* x   = (const float*)d_in[0];   // 4*32*56*56
    const float* w   = (const float*)d_in[1];   // 64*32*3*3
    float*       out = (float*)d_out;           // 4*64*56*56
    float*       ws  = (float*)d_ws;

    prep<<<PADBLKS + 1, 256, 0, stream>>>(x, w, ws);
    dim3 grid(IMG / 64, OCH / OT, BB);          // 49 x 16 x 4 = 3136 blocks
    minconv_kernel<<<grid, 128, 0, stream>>>(ws, w, out);
}

// Round 4
// 85.012 us; speedup vs baseline: 1.1390x; 1.1286x over previous
//
#include <hip/hip_runtime.h>

#define CIN  32
#define OCH  64
#define HH   56
#define WW   56
#define BB   4
#define OT   4                  // output channels per block
#define IMG  (HH * WW)          // 3136
#define NW   18432              // 64*32*3*3
#define PH   58
#define PW   58
#define PIMG (PH * PW)          // 3364 padded image
#define NPAD (BB * CIN * PIMG)  // 430592 padded elements
#define PADBLKS (NPAD / 256)    // 1682 (exact)
#define XOFF 64                 // padded x starts at ws + 64 floats (256B aligned)

typedef float vf2 __attribute__((ext_vector_type(2)));  // -> v_pk_add_f32

// One dispatch does BOTH jobs:
//   blocks 0..1681 : write zero-padded (B,C,58,58) copy of x into ws+XOFF
//   block  1682    : |w| mean -> ws[0]  (single block, plain store, no atomic)
__global__ __launch_bounds__(256) void prep(const float* __restrict__ x,
                                            const float* __restrict__ w,
                                            float* __restrict__ ws) {
    if (blockIdx.x == PADBLKS) {
        float s = 0.f;
        const float4* w4 = reinterpret_cast<const float4*>(w);
        #pragma unroll
        for (int k = 0; k < 18; ++k) {
            float4 v = w4[k * 256 + threadIdx.x];
            s += fabsf(v.x) + fabsf(v.y) + fabsf(v.z) + fabsf(v.w);
        }
        #pragma unroll
        for (int off = 32; off; off >>= 1) s += __shfl_down(s, off);
        __shared__ float sm[4];
        if ((threadIdx.x & 63) == 0) sm[threadIdx.x >> 6] = s;
        __syncthreads();
        if (threadIdx.x == 0)
            ws[0] = (sm[0] + sm[1] + sm[2] + sm[3]) * (1.0f / (float)NW);
        return;
    }
    int idx = blockIdx.x * 256 + threadIdx.x;          // 0..NPAD-1
    int bc  = idx / PIMG;
    int r   = idx - bc * PIMG;
    int ph  = r / PW;
    int pw  = r - ph * PW;
    int hh  = ph - 1, wc = pw - 1;
    float v = 0.f;
    if ((unsigned)hh < (unsigned)HH && (unsigned)wc < (unsigned)WW)
        v = x[bc * IMG + hh * WW + wc];                // coalesced within rows
    ws[XOFF + idx] = v;
}

// block = 128 threads = 2 waves over the SAME 64 pixels; wave wv handles
// channels [wv*16, wv*16+16).
// CRITICAL (R3 lesson): the weight base must be provably WAVE-UNIFORM-SCALAR
// or all weight reads become per-lane global_load_dword (288/wave, 6x slower).
// threadIdx-derived values are "divergent" to LLVM even when wave-uniform;
// __builtin_amdgcn_readfirstlane forces them into an SGPR -> s_load weights.
__global__ __launch_bounds__(128) void minconv_kernel(const float* __restrict__ ws,
                                                      const float* __restrict__ wts,
                                                      float* __restrict__ out) {
    const float* xp = ws + XOFF;
    const int lane = threadIdx.x & 63;
    const int wv   = threadIdx.x >> 6;                 // 0/1: channel half
    const int wvs  = __builtin_amdgcn_readfirstlane(wv);   // SGPR copy of wv
    const int hw = blockIdx.x * 64 + lane;             // 0..3135 exact
    const int o0 = blockIdx.y * OT;
    const int b  = blockIdx.z;
    const int h  = hw / WW;
    const int w  = hw - h * WW;

    const float mu = ws[0];                            // uniform s_load, issued early

    // lane base for this (b, c-half, pixel); taps at +kh*PW+kw, channel B at +PIMG
    const float* xq = xp + (size_t)b * (CIN * PIMG) + (wvs * 16) * PIMG + h * PW + w;
    const float* wb = wts + o0 * (CIN * 9) + (wvs * 16) * 9;  // SCALAR -> s_load

    vf2 acc0 = (vf2)(0.f), acc1 = (vf2)(0.f);
    vf2 acc2 = (vf2)(0.f), acc3 = (vf2)(0.f);

    #pragma unroll
    for (int cp = 0; cp < 8; ++cp) {                   // 8 channel-pairs per wave
        const float* xA = xq + cp * 2 * PIMG;          // channel 2cp
        const float* xB = xA + PIMG;                   // channel 2cp+1
        float xa[9], xc[9];
        #pragma unroll
        for (int kh = 0; kh < 3; ++kh)
            #pragma unroll
            for (int kw = 0; kw < 3; ++kw) {
                xa[kh * 3 + kw] = xA[kh * PW + kw];
                xc[kh * 3 + kw] = xB[kh * PW + kw];
            }
        #pragma unroll
        for (int oo = 0; oo < OT; ++oo) {
            const float* wpA = wb + oo * (CIN * 9) + cp * 18;  // scalar -> s_load
            const float* wpB = wpA + 9;
            vf2 a = (vf2)(0.f);
            #pragma unroll
            for (int t = 0; t < 9; ++t) {
                vf2 m;
                m.x = fminf(xa[t], wpA[t]);
                m.y = fminf(xc[t], wpB[t]);
                a += m;                                // v_pk_add_f32
            }
            switch (oo) {                              // literal acc indices only
                case 0: acc0 += a; break;
                case 1: acc1 += a; break;
                case 2: acc2 += a; break;
                case 3: acc3 += a; break;
            }
        }
    }

    // cross-wave combine: wave0 keeps oo 0,1; wave1 keeps oo 2,3.
    __shared__ vf2 red[2][2][64];                      // [src_wave][j][lane], 2 KiB
    if (wv == 0) {
        red[0][0][lane] = acc2;
        red[0][1][lane] = acc3;
    } else {
        red[1][0][lane] = acc0;
        red[1][1][lane] = acc1;
    }
    __syncthreads();

    float* ob = out + ((size_t)b * OCH + o0) * IMG + hw;
    if (wv == 0) {
        vf2 s0 = acc0 + red[1][0][lane];
        vf2 s1 = acc1 + red[1][1][lane];
        ob[0]       = mu * (s0.x + s0.y);
        ob[IMG]     = mu * (s1.x + s1.y);
    } else {
        vf2 s0 = acc2 + red[0][0][lane];
        vf2 s1 = acc3 + red[0][1][lane];
        ob[2 * IMG] = mu * (s0.x + s0.y);
        ob[3 * IMG] = mu * (s1.x + s1.y);
    }
}

extern "C" void kernel_launch(void* const* d_in, const int* in_sizes, int n_in,
                              void* d_out, int out_size, void* d_ws, size_t ws_size,
                              hipStream_t stream) {
    const float* x   = (const float*)d_in[0];   // 4*32*56*56
    const float* w   = (const float*)d_in[1];   // 64*32*3*3
    float*       out = (float*)d_out;           // 4*64*56*56
    float*       ws  = (float*)d_ws;

    prep<<<PADBLKS + 1, 256, 0, stream>>>(x, w, ws);
    dim3 grid(IMG / 64, OCH / OT, BB);          // 49 x 16 x 4 = 3136 blocks
    minconv_kernel<<<grid, 128, 0, stream>>>(ws, w, out);
}

// Round 5
// 73.289 us; speedup vs baseline: 1.3212x; 1.1600x over previous
//
#include <hip/hip_runtime.h>

#define CIN  32
#define OCH  64
#define HH   56
#define WW   56
#define BB   4
#define OT   4                  // output channels per block
#define IMG  (HH * WW)          // 3136
#define NW   18432              // 64*32*3*3
#define PH   58
#define PW   58
#define PIMG (PH * PW)          // 3364 padded image
#define NXPK (BB * (CIN/2) * PIMG)   // 215296 packed x uints
#define XPKBLKS (NXPK / 256)         // 841 (exact)
#define NWPK (OCH * (CIN/2) * 9)     // 9216 packed weight uints
#define WPKBLKS (NWPK / 256)         // 36 (exact)
#define WOFFu 64                     // packed weights at wsu+64 (uint units)
#define XOFFu (WOFFu + NWPK)         // 9280: packed x follows (256B aligned)

typedef _Float16 h2 __attribute__((ext_vector_type(2)));   // v_pk_*_f16 / fdot2

// One dispatch, three jobs (fp16 channel-pair packing):
//   blocks [0,841)    : zero-padded x -> fp16 pairs (ch 2cp, 2cp+1) at wsu+XOFFu
//   blocks [841,877)  : weights       -> fp16 pairs at wsu+WOFFu
//   block  877        : mu = mean|w| (fp32) -> ws[0]
__global__ __launch_bounds__(256) void prep(const float* __restrict__ x,
                                            const float* __restrict__ w,
                                            float* __restrict__ ws) {
    unsigned* wsu = reinterpret_cast<unsigned*>(ws);
    if (blockIdx.x < XPKBLKS) {
        int idx = blockIdx.x * 256 + threadIdx.x;      // 0..NXPK-1
        int bc  = idx / PIMG;                          // b*16 + cp
        int r   = idx - bc * PIMG;
        int ph  = r / PW;
        int pw  = r - ph * PW;
        int hh  = ph - 1, wc = pw - 1;
        float v0 = 0.f, v1 = 0.f;
        if ((unsigned)hh < (unsigned)HH && (unsigned)wc < (unsigned)WW) {
            int base = ((bc >> 4) * CIN + (bc & 15) * 2) * IMG + hh * WW + wc;
            v0 = x[base];                              // channel 2cp   (coalesced)
            v1 = x[base + IMG];                        // channel 2cp+1
        }
        h2 p; p.x = (_Float16)v0; p.y = (_Float16)v1;
        wsu[XOFFu + idx] = __builtin_bit_cast(unsigned, p);
        return;
    }
    if (blockIdx.x < XPKBLKS + WPKBLKS) {
        int idx = (blockIdx.x - XPKBLKS) * 256 + threadIdx.x;  // 0..NWPK-1
        int t    = idx % 9;
        int rest = idx / 9;                            // oo*16 + cp
        int cp   = rest & 15;
        int oo   = rest >> 4;
        int base = oo * (CIN * 9) + cp * 18 + t;
        h2 p; p.x = (_Float16)w[base]; p.y = (_Float16)w[base + 9];
        wsu[WOFFu + idx] = __builtin_bit_cast(unsigned, p);
        return;
    }
    // |w| mean (fp32 source) -> ws[0]
    float s = 0.f;
    const float4* w4 = reinterpret_cast<const float4*>(w);
    #pragma unroll
    for (int k = 0; k < 18; ++k) {
        float4 v = w4[k * 256 + threadIdx.x];
        s += fabsf(v.x) + fabsf(v.y) + fabsf(v.z) + fabsf(v.w);
    }
    #pragma unroll
    for (int off = 32; off; off >>= 1) s += __shfl_down(s, off);
    __shared__ float sm[4];
    if ((threadIdx.x & 63) == 0) sm[threadIdx.x >> 6] = s;
    __syncthreads();
    if (threadIdx.x == 0)
        ws[0] = (sm[0] + sm[1] + sm[2] + sm[3]) * (1.0f / (float)NW);
}

// block = 128 threads = 2 waves over the SAME 64 pixels; wave wv handles
// channel-pairs [wv*8, wv*8+8). Inner step per tap-pair is 2 instrs:
//   v_pk_min_f16 (both channels) + v_dot2_f32_f16 with (1,1) -> fp32 acc.
// R3 lesson: weight indices must be SGPR-provable (readfirstlane on wv).
// R2 lesson: no runtime-indexed ext_vector arrays (literal acc names).
__global__ __launch_bounds__(128) void minconv_kernel(const float* __restrict__ ws,
                                                      const float* __restrict__ wts,
                                                      float* __restrict__ out) {
    const unsigned* wsu = reinterpret_cast<const unsigned*>(ws);
    const int lane = threadIdx.x & 63;
    const int wv   = threadIdx.x >> 6;
    const int wvs  = __builtin_amdgcn_readfirstlane(wv);   // SGPR copy
    const int hw = blockIdx.x * 64 + lane;             // 0..3135 exact
    const int o0 = blockIdx.y * OT;
    const int b  = blockIdx.z;
    const int h  = hw / WW;
    const int w  = hw - h * WW;

    const float mu = ws[0];                            // uniform s_load

    const int cp0 = wvs * 8;                           // this wave's channel-pairs
    const unsigned* xq = wsu + XOFFu + (size_t)(b * 16 + cp0) * PIMG + h * PW + w;
    const unsigned* wq = wsu + WOFFu;                  // scalar-indexed -> s_load

    h2 ones; ones.x = (_Float16)1.f; ones.y = (_Float16)1.f;
    float acc0 = 0.f, acc1 = 0.f, acc2 = 0.f, acc3 = 0.f;

    #pragma unroll
    for (int cp = 0; cp < 8; ++cp) {
        h2 xv[9];                                      // literal indices only
        #pragma unroll
        for (int kh = 0; kh < 3; ++kh)
            #pragma unroll
            for (int kw = 0; kw < 3; ++kw)
                xv[kh * 3 + kw] = __builtin_bit_cast(h2, xq[cp * PIMG + kh * PW + kw]);
        #pragma unroll
        for (int oo = 0; oo < OT; ++oo) {
            const int wbase = ((o0 + oo) * 16 + (cp0 + cp)) * 9;   // scalar
            float a = 0.f;
            #pragma unroll
            for (int t = 0; t < 9; ++t) {
                h2 wp = __builtin_bit_cast(h2, wq[wbase + t]);      // s_load
                h2 m  = __builtin_elementwise_min(xv[t], wp);       // v_pk_min_f16
                a = __builtin_amdgcn_fdot2(m, ones, a, false);      // v_dot2_f32_f16
            }
            switch (oo) {
                case 0: acc0 += a; break;
                case 1: acc1 += a; break;
                case 2: acc2 += a; break;
                case 3: acc3 += a; break;
            }
        }
    }

    // cross-wave combine: wave0 keeps oo 0,1; wave1 keeps oo 2,3.
    __shared__ float red[2][2][64];                    // 1 KiB
    if (wv == 0) {
        red[0][0][lane] = acc2;
        red[0][1][lane] = acc3;
    } else {
        red[1][0][lane] = acc0;
        red[1][1][lane] = acc1;
    }
    __syncthreads();

    float* ob = out + ((size_t)b * OCH + o0) * IMG + hw;
    if (wv == 0) {
        ob[0]       = mu * (acc0 + red[1][0][lane]);
        ob[IMG]     = mu * (acc1 + red[1][1][lane]);
    } else {
        ob[2 * IMG] = mu * (acc2 + red[0][0][lane]);
        ob[3 * IMG] = mu * (acc3 + red[0][1][lane]);
    }
}

extern "C" void kernel_launch(void* const* d_in, const int* in_sizes, int n_in,
                              void* d_out, int out_size, void* d_ws, size_t ws_size,
                              hipStream_t stream) {
    const float* x   = (const float*)d_in[0];   // 4*32*56*56
    const float* w   = (const float*)d_in[1];   // 64*32*3*3
    float*       out = (float*)d_out;           // 4*64*56*56
    float*       ws  = (float*)d_ws;

    prep<<<XPKBLKS + WPKBLKS + 1, 256, 0, stream>>>(x, w, ws);
    dim3 grid(IMG / 64, OCH / OT, BB);          // 49 x 16 x 4 = 3136 blocks
    minconv_kernel<<<grid, 128, 0, stream>>>(ws, w, out);
}